// Round 4
// baseline (170.410 us; speedup 1.0000x reference)
//
#include <hip/hip_runtime.h>
#include <hip/hip_bf16.h>

// HSA prefill, MFMA bf16, S-split, 8 wg/CU occupancy version.
// O = sum_s w_s * softmax(K_s Q^T) V_s  (per-block softmax => s independent)
// Grid 2048 = (l 256) x (h 2) x (split 4); 4 s-blocks per wg; atomicAdd combine.
//
// Key changes vs R3: K staged to LDS with COALESCED float4 loads (direct-global
// K frags caused ~16 line-transactions per wave-instr = TA serialization);
// K-tile and V^T-tile UNION one 17.4 KB buffer (K fully consumed by score
// MFMAs before V staging, barrier-separated) -> LDS 19968 B -> 8 wg/CU;
// __launch_bounds__(256,8) caps VGPR at 64 (dropped wv/biv register caches).
// All LDS access patterns are <=2-way bank-aliased (free on gfx950, m136).

namespace {

constexpr int kLq = 256, kHQ = 32, kH = 2, kG = 16, kD = 128, kS = 16, kBS = 64;
constexpr int kSplit = 4;               // s-blocks per wg
constexpr int kKVRow = kH * kD;         // 256 floats between consecutive kv rows
constexpr float kScaleLog2e = 0.08838834764831845f * 1.4426950408889634f;

constexpr int kKStr = 136;  // K view row stride (shorts): 272 B, b128-aligned
constexpr int kVStr = 68;   // V^T view row stride (shorts): 136 B, b64-aligned
constexpr int kPStr = 72;   // P_s row stride (shorts): 144 B

typedef short s16x8 __attribute__((ext_vector_type(8)));
typedef short s16x4 __attribute__((ext_vector_type(4)));
typedef float f32x4 __attribute__((ext_vector_type(4)));

union U32BF2 { unsigned int u; __hip_bfloat162 h; };

static __device__ inline unsigned int pk_bf16(float a, float b) {
    U32BF2 z; z.h = __float22bfloat162_rn(make_float2(a, b));
    return z.u;
}

__global__ __launch_bounds__(256, 8)
void hsa_mfma_kernel(const float* __restrict__ q,
                     const float* __restrict__ k,
                     const float* __restrict__ v,
                     const float* __restrict__ w,
                     const int*   __restrict__ bidx,
                     float* __restrict__ out)
{
    // Union buffer: K view [u][d] = KV_s[u*136 + d] (64 rows),
    //               V^T view [d][u] = KV_s[d*68 + u] (128 rows). 8704 shorts.
    __shared__ __align__(16) unsigned short KV_s[kBS * kKStr];
    __shared__ __align__(16) unsigned short P_s[kG][kPStr];
    __shared__ float psum[4][kG];

    const int bid   = blockIdx.x;        // 0..2047
    const int l     = bid >> 3;
    const int h     = (bid >> 2) & 1;
    const int split = bid & 3;
    const int t     = threadIdx.x;
    const int wave  = t >> 6;
    const int lane  = t & 63;
    const int n     = lane & 15;         // N index (g) / M-local index
    const int quad  = lane >> 4;         // 0..3

    // ---- Q B-fragments (N=g side): lane g=n, k=d = st*32 + quad*8 + j ----
    s16x8 qf[4];
    {
        const float* qb = q + (size_t)(l * kHQ + h * kG + n) * kD + quad * 8;
        #pragma unroll
        for (int st = 0; st < 4; ++st) {
            const float4 f0 = *(const float4*)(qb + st * 32);
            const float4 f1 = *(const float4*)(qb + st * 32 + 4);
            union { s16x8 v; unsigned int u[4]; } z;
            z.u[0] = pk_bf16(f0.x, f0.y); z.u[1] = pk_bf16(f0.z, f0.w);
            z.u[2] = pk_bf16(f1.x, f1.y); z.u[3] = pk_bf16(f1.z, f1.w);
            qf[st] = z.v;
        }
    }

    f32x4 oacc0 = {0.f, 0.f, 0.f, 0.f};  // O^T d-tile 2*wave
    f32x4 oacc1 = {0.f, 0.f, 0.f, 0.f};  // O^T d-tile 2*wave+1

    const int kr = t >> 5;                // K staging: row 0..7 per pass
    const int kc = (t & 31) << 2;         // K staging: float col 0..124

    #pragma unroll 1
    for (int j = 0; j < kSplit; ++j) {
        const int bi = bidx[(size_t)(l * kH + h) * kS + split * 4 + j];  // wg-uniform
        if (bi < 0) continue;             // barrier-safe (uniform)

        // per-lane weight for g=n, this s (issue early; needed after B3)
        const float wj = w[(size_t)(l * kHQ + h * kG + n) * kS + split * 4 + j];

        __syncthreads();                  // B1: prior block's V_t/P_s reads done

        // ---- stage K block -> K view (coalesced: 2 lines per wave-instr) ----
        {
            const float* kb = k + (size_t)(bi * kBS) * kKVRow + h * kD + kc;
            #pragma unroll 4
            for (int pass = 0; pass < 8; ++pass) {
                const int u = pass * 8 + kr;
                const float4 f = *(const float4*)(kb + (size_t)u * kKVRow);
                const unsigned long long pq =
                    ((unsigned long long)pk_bf16(f.z, f.w) << 32) | pk_bf16(f.x, f.y);
                *(unsigned long long*)&KV_s[u * kKStr + kc] = pq;
            }
        }
        __syncthreads();                  // B2: K visible

        // ---- scores: S^T[u][g], wave owns u-tile = wave ----
        f32x4 sc = {0.f, 0.f, 0.f, 0.f};
        {
            const int u = wave * 16 + n;
            #pragma unroll
            for (int st = 0; st < 4; ++st) {
                const s16x8 af = *(const s16x8*)&KV_s[u * kKStr + st * 32 + quad * 8];
                sc = __builtin_amdgcn_mfma_f32_16x16x32_bf16(af, qf[st], sc, 0, 0, 0);
            }
        }

        // ---- per-block softmax over 64 u for g=n (partial) ----
        const float e0 = exp2f(sc[0] * kScaleLog2e);
        const float e1 = exp2f(sc[1] * kScaleLog2e);
        const float e2 = exp2f(sc[2] * kScaleLog2e);
        const float e3 = exp2f(sc[3] * kScaleLog2e);
        float part = (e0 + e1) + (e2 + e3);      // wave's 16-u partial (per g)
        part += __shfl_xor(part, 16);
        part += __shfl_xor(part, 32);
        if (quad == 0) psum[wave][n] = part;

        __syncthreads();                  // B3: psum visible + K reads done

        // ---- stage V block transposed -> V^T view (same buffer) ----
        {
            const float* vb = v + (size_t)(bi * kBS) * kKVRow + h * kD;
            #pragma unroll 4
            for (int pass = 0; pass < 8; ++pass) {
                const int u0 = (pass * 4 + wave) * 2;
                const float* r0 = vb + (size_t)u0 * kKVRow;
                const float* r1 = r0 + kKVRow;
                #pragma unroll
                for (int i = 0; i < 2; ++i) {
                    const int d = i * 64 + lane;
                    *(unsigned int*)&KV_s[d * kVStr + u0] = pk_bf16(r0[d], r1[d]);
                }
            }
        }

        // ---- finish softmax; weight; P -> LDS (B-layout) ----
        {
            const float tot  = psum[0][n] + psum[1][n] + psum[2][n] + psum[3][n];
            const float coef = wj / tot;
            // lane holds P[g=n][u = wave*16 + quad*4 + r], r=0..3
            const unsigned long long pq =
                ((unsigned long long)pk_bf16(e2 * coef, e3 * coef) << 32) |
                pk_bf16(e0 * coef, e1 * coef);
            *(unsigned long long*)&P_s[n][wave * 16 + quad * 4] = pq;
        }
        __syncthreads();                  // B4: V^T + P_s visible

        // ---- PV: O^T[d][g] += V^T · P^T; wave owns d-tiles {2w, 2w+1} ----
        #pragma unroll
        for (int st = 0; st < 2; ++st) {
            const s16x8 bf = *(const s16x8*)&P_s[n][st * 32 + quad * 8];
            const int ub = st * 32 + quad * 8;
            {
                const int d = wave * 32 + n;
                const s16x4 a0 = *(const s16x4*)&KV_s[d * kVStr + ub];
                const s16x4 a1 = *(const s16x4*)&KV_s[d * kVStr + ub + 4];
                const s16x8 af = __builtin_shufflevector(a0, a1, 0,1,2,3,4,5,6,7);
                oacc0 = __builtin_amdgcn_mfma_f32_16x16x32_bf16(af, bf, oacc0, 0, 0, 0);
            }
            {
                const int d = wave * 32 + 16 + n;
                const s16x4 a0 = *(const s16x4*)&KV_s[d * kVStr + ub];
                const s16x4 a1 = *(const s16x4*)&KV_s[d * kVStr + ub + 4];
                const s16x8 af = __builtin_shufflevector(a0, a1, 0,1,2,3,4,5,6,7);
                oacc1 = __builtin_amdgcn_mfma_f32_16x16x32_bf16(af, bf, oacc1, 0, 0, 0);
            }
        }
    }

    // ---- epilogue: atomic-accumulate partial O^T into out[l][h*16+g][d] ----
    {
        float* ob = out + (size_t)(l * kHQ + h * kG + n) * kD;
        const int d0 = wave * 32 + quad * 4;
        #pragma unroll
        for (int i = 0; i < 4; ++i) {
            atomicAdd(ob + d0 + i,      oacc0[i]);
            atomicAdd(ob + d0 + 16 + i, oacc1[i]);
        }
    }
}

} // namespace

extern "C" void kernel_launch(void* const* d_in, const int* in_sizes, int n_in,
                              void* d_out, int out_size, void* d_ws, size_t ws_size,
                              hipStream_t stream)
{
    const float* q    = (const float*)d_in[0];
    const float* k    = (const float*)d_in[1];
    const float* v    = (const float*)d_in[2];
    const float* w    = (const float*)d_in[3];
    const int*   bidx = (const int*)d_in[4];
    float* out = (float*)d_out;

    hipMemsetAsync(out, 0, (size_t)out_size * sizeof(float), stream);
    hsa_mfma_kernel<<<dim3(kLq * kH * kSplit), dim3(256), 0, stream>>>(q, k, v, w, bidx, out);
}

// Round 5
// 126.564 us; speedup vs baseline: 1.3464x; 1.3464x over previous
//
#include <hip/hip_runtime.h>
#include <hip/hip_bf16.h>

// HSA prefill R5: two-kernel design.
//
// Insight: block_indices < Lkv/BS = 64 -> only 64 distinct KV blocks per head
// (4.2 MB as bf16). Pre-pack K and V ONCE into bf16 arrays laid out in exact
// MFMA A-fragment order, so the main kernel's every K/V access is a single
// fully-coalesced global dwordx4 (L2-resident), with no LDS staging, no
// per-use cvt, and no barriers in the hot loop.
//
// Main kernel: wg = (l,h), 512 thr = 8 waves, each wave owns 2 s-blocks
// end-to-end (scores 16 MFMA -> fully intra-wave softmax -> P via per-wave
// private LDS slice (no barrier; wave-coherent) -> PV 16 MFMA). Output
// combined across waves with LDS ds_add_f32, then direct coalesced stores:
// NO global atomics, NO memset. Only 2 wg-wide barriers total.
// __launch_bounds__(512,4): VGPR cap 128 (R4 lesson: 8 waves/EU -> 32 VGPR
// -> scratch spills -> FETCH/WRITE explosion).

namespace {

constexpr int kLq = 256, kHQ = 32, kH = 2, kG = 16, kD = 128, kS = 16, kBS = 64;
constexpr int kNB = 64;                    // Lkv / BS: distinct blocks per head
constexpr float kScaleLog2e = 0.08838834764831845f * 1.4426950408889634f;

constexpr int kKPackN = kH * kNB * 16 * 64;  // uint4 elements (2 MB)
constexpr int kPStr   = 72;                  // P slice g-stride (shorts), 144 B (16B-aligned rows)

typedef short s16x8 __attribute__((ext_vector_type(8)));
typedef float f32x4 __attribute__((ext_vector_type(4)));

union U32BF2 { unsigned int u; __hip_bfloat162 h; };
union FragU  { uint4 u; s16x8 v; };

static __device__ inline unsigned int pk_bf16(float a, float b) {
    U32BF2 z; z.h = __float22bfloat162_rn(make_float2(a, b));
    return z.u;
}

// ---------------- pack kernel: K,V fp32 -> bf16 in MFMA A-frag order --------
// K_packed idx = ((h*64+blk)*16 + t*4+st)*64 + lane  (lane = quad*16 + n)
//   holds K[u = blk*64 + t*16 + n][h][d = st*32 + quad*8 + j], j=0..7
// V_packed idx = ((h*64+blk)*16 + dt*2+st)*64 + lane
//   holds V[u = blk*64 + st*32 + quad*8 + j][h][d = dt*16 + n], j=0..7
__global__ __launch_bounds__(256)
void pack_kv(const float* __restrict__ k, const float* __restrict__ v,
             uint4* __restrict__ kp, uint4* __restrict__ vp)
{
    const int idx  = blockIdx.x * 256 + threadIdx.x;   // 0 .. 2*131071
    const bool isV = idx >= kKPackN;
    const int i    = isV ? idx - kKPackN : idx;
    const int lane = i & 63, n = lane & 15, quad = lane >> 4;
    const int c    = (i >> 6) & 15;
    const int blk  = (i >> 10) & 63;
    const int h    = i >> 16;

    if (!isV) {
        const int t = c >> 2, st = c & 3;
        const int u = blk * 64 + t * 16 + n;
        const float* src = k + ((size_t)u * kH + h) * kD + st * 32 + quad * 8;
        const float4 f0 = *(const float4*)(src);
        const float4 f1 = *(const float4*)(src + 4);
        uint4 o;
        o.x = pk_bf16(f0.x, f0.y); o.y = pk_bf16(f0.z, f0.w);
        o.z = pk_bf16(f1.x, f1.y); o.w = pk_bf16(f1.z, f1.w);
        kp[i] = o;
    } else {
        const int dt = c >> 1, st = c & 1;
        const int d  = dt * 16 + n;
        const int u0 = blk * 64 + st * 32 + quad * 8;
        float f[8];
        #pragma unroll
        for (int j = 0; j < 8; ++j)
            f[j] = v[((size_t)(u0 + j) * kH + h) * kD + d];
        uint4 o;
        o.x = pk_bf16(f[0], f[1]); o.y = pk_bf16(f[2], f[3]);
        o.z = pk_bf16(f[4], f[5]); o.w = pk_bf16(f[6], f[7]);
        vp[i] = o;
    }
}

// ---------------- main kernel ----------------------------------------------
__global__ __launch_bounds__(512, 4)
void hsa_main(const float* __restrict__ q, const float* __restrict__ w,
              const int* __restrict__ bidx, const uint4* __restrict__ kp,
              const uint4* __restrict__ vp, float* __restrict__ out)
{
    __shared__ __align__(16) unsigned short P_s[8 * kG * kPStr];  // per-wave slices
    __shared__ float O_red[kD * 17];                              // [d][g], stride 17

    const int bid  = blockIdx.x;          // 0..511
    const int l    = bid >> 1;
    const int h    = bid & 1;
    const int tid  = threadIdx.x;
    const int wave = tid >> 6;
    const int lane = tid & 63;
    const int n    = lane & 15;
    const int quad = lane >> 4;

    for (int i = tid; i < kD * 17; i += 512) O_red[i] = 0.f;

    // Q B-frags: lane g=n, k = st*32 + quad*8 + j
    s16x8 qf[4];
    {
        const float* qb = q + ((size_t)l * kHQ + h * kG + n) * kD + quad * 8;
        #pragma unroll
        for (int st = 0; st < 4; ++st) {
            const float4 f0 = *(const float4*)(qb + st * 32);
            const float4 f1 = *(const float4*)(qb + st * 32 + 4);
            union { s16x8 v; unsigned int u[4]; } z;
            z.u[0] = pk_bf16(f0.x, f0.y); z.u[1] = pk_bf16(f0.z, f0.w);
            z.u[2] = pk_bf16(f1.x, f1.y); z.u[3] = pk_bf16(f1.z, f1.w);
            qf[st] = z.v;
        }
    }

    __syncthreads();                      // O_red zeroed before any ds_add

    unsigned short* Pw = &P_s[wave * kG * kPStr];
    f32x4 oacc[8];
    #pragma unroll
    for (int dt = 0; dt < 8; ++dt) oacc[dt] = (f32x4){0.f, 0.f, 0.f, 0.f};

    #pragma unroll 1
    for (int js = 0; js < 2; ++js) {
        const int s  = wave * 2 + js;
        const int bi = bidx[(l * kH + h) * kS + s];
        if (bi < 0) continue;             // wave-local skip: no barriers inside

        const float wj  = w[((size_t)l * kHQ + h * kG + n) * kS + s];
        const int  base = (h * kNB + bi) * 16 * 64;   // uint4 index

        // ---- scores: wave computes all 4 u-tiles of S^T (64u x 16g) ----
        f32x4 sc[4];
        #pragma unroll
        for (int t = 0; t < 4; ++t) sc[t] = (f32x4){0.f, 0.f, 0.f, 0.f};
        #pragma unroll
        for (int t = 0; t < 4; ++t)
            #pragma unroll
            for (int st = 0; st < 4; ++st) {
                FragU a; a.u = kp[base + (t * 4 + st) * 64 + lane];
                sc[t] = __builtin_amdgcn_mfma_f32_16x16x32_bf16(a.v, qf[st], sc[t], 0, 0, 0);
            }

        // ---- fully intra-wave softmax over all 64 u, per g=n ----
        float e[4][4];
        float part = 0.f;
        #pragma unroll
        for (int t = 0; t < 4; ++t)
            #pragma unroll
            for (int r = 0; r < 4; ++r) {
                e[t][r] = exp2f(sc[t][r] * kScaleLog2e);
                part += e[t][r];
            }
        part += __shfl_xor(part, 16);
        part += __shfl_xor(part, 32);     // lanes of same n now hold full sum
        const float coef = wj / part;

        // ---- P -> per-wave LDS slice (B-frag order); wave-coherent ----
        #pragma unroll
        for (int t = 0; t < 4; ++t) {
            const unsigned long long pq =
                ((unsigned long long)pk_bf16(e[t][2] * coef, e[t][3] * coef) << 32) |
                pk_bf16(e[t][0] * coef, e[t][1] * coef);
            *(unsigned long long*)&Pw[n * kPStr + t * 16 + quad * 4] = pq;
        }
        const s16x8 bf0 = *(const s16x8*)&Pw[n * kPStr + quad * 8];
        const s16x8 bf1 = *(const s16x8*)&Pw[n * kPStr + 32 + quad * 8];

        // ---- PV: O^T[d][g] += V^T P^T, 8 d-tiles ----
        #pragma unroll
        for (int dt = 0; dt < 8; ++dt) {
            FragU a0, a1;
            a0.u = vp[base + (dt * 2 + 0) * 64 + lane];
            a1.u = vp[base + (dt * 2 + 1) * 64 + lane];
            oacc[dt] = __builtin_amdgcn_mfma_f32_16x16x32_bf16(a0.v, bf0, oacc[dt], 0, 0, 0);
            oacc[dt] = __builtin_amdgcn_mfma_f32_16x16x32_bf16(a1.v, bf1, oacc[dt], 0, 0, 0);
        }
    }

    // ---- combine across waves in LDS (ds_add_f32), then store ----
    // C-layout: col=n=g, row = quad*4 + r -> d = dt*16 + quad*4 + r
    #pragma unroll
    for (int dt = 0; dt < 8; ++dt)
        #pragma unroll
        for (int r = 0; r < 4; ++r)
            atomicAdd(&O_red[(dt * 16 + quad * 4 + r) * 17 + n], oacc[dt][r]);

    __syncthreads();

    // out[l][h*16+g][d]; thread -> one float4: g = tid>>5, d0 = (tid&31)*4
    {
        float* ob = out + ((size_t)l * kHQ + h * kG) * kD;
        const int g  = tid >> 5;
        const int d0 = (tid & 31) << 2;
        const float4 val = make_float4(O_red[(d0 + 0) * 17 + g],
                                       O_red[(d0 + 1) * 17 + g],
                                       O_red[(d0 + 2) * 17 + g],
                                       O_red[(d0 + 3) * 17 + g]);
        *(float4*)(ob + (size_t)g * kD + d0) = val;
    }
}

} // namespace

extern "C" void kernel_launch(void* const* d_in, const int* in_sizes, int n_in,
                              void* d_out, int out_size, void* d_ws, size_t ws_size,
                              hipStream_t stream)
{
    const float* q    = (const float*)d_in[0];
    const float* k    = (const float*)d_in[1];
    const float* v    = (const float*)d_in[2];
    const float* w    = (const float*)d_in[3];
    const int*   bidx = (const int*)d_in[4];
    float* out = (float*)d_out;

    uint4* kp = (uint4*)d_ws;                                   // 2 MB
    uint4* vp = (uint4*)((char*)d_ws + (size_t)kKPackN * 16);   // 2 MB

    pack_kv<<<dim3(2 * kKPackN / 256), dim3(256), 0, stream>>>(k, v, kp, vp);
    hsa_main<<<dim3(kLq * kH), dim3(512), 0, stream>>>(q, w, bidx, kp, vp, out);
}

// Round 6
// 114.481 us; speedup vs baseline: 1.4885x; 1.1055x over previous
//
#include <hip/hip_runtime.h>
#include <hip/hip_bf16.h>

// HSA prefill R6.
// pack_kv: LDS-transpose repack of K,V -> bf16 MFMA-frag order (coalesced both
//   sides; R5's V-path did 8x stride-1KB scalar loads = 68 us of the 126).
// hsa_main: wg=(l,h) 256 thr; wave owns 4 s-blocks; K/V frags in explicit
//   16-reg arrays for MLP=16 (R5 had VGPR_Count=60 -> MLP~1 -> serialized
//   ~550cyc L2 loads). V loads issued before score MFMAs; next-block K
//   prefetched before PV. launch_bounds(256,2): VGPR cap 256 (no R4 spills).
//   Invalid blocks handled branchlessly (wj=0); this dataset has none.

namespace {

constexpr int kLq = 256, kHQ = 32, kH = 2, kG = 16, kD = 128, kS = 16;
constexpr int kNB = 64;                    // Lkv/BS: distinct blocks per head
constexpr float kScaleLog2e = 0.08838834764831845f * 1.4426950408889634f;

constexpr int kKPackN = kH * kNB * 16 * 64;  // uint4 elems per array (2 MB)
constexpr int kPStr   = 72;                  // P slice g-stride (shorts)
constexpr int kSStr   = 136;                 // pack LDS row stride (shorts)

typedef short s16x8 __attribute__((ext_vector_type(8)));
typedef float f32x4 __attribute__((ext_vector_type(4)));

union U32BF2 { unsigned int u; __hip_bfloat162 h; };
union FragU  { uint4 u; s16x8 v; };

static __device__ inline unsigned int pk_bf16(float a, float b) {
    U32BF2 z; z.h = __float22bfloat162_rn(make_float2(a, b));
    return z.u;
}

// ---------------- pack kernel --------------------------------------------
// grid 256: bid = h*128 + blk*2 + isV. 256 thr.
// K_packed idx = ((h*64+blk)*16 + t*4+st)*64 + lane (lane = quad*16+n)
//   holds K[u = blk*64 + t*16 + n][h][d = st*32 + quad*8 + j]
// V_packed idx = ((h*64+blk)*16 + dt*2+st)*64 + lane
//   holds V[u = blk*64 + st*32 + quad*8 + j][h][d = dt*16 + n]
__global__ __launch_bounds__(256)
void pack_kv(const float* __restrict__ k, const float* __restrict__ v,
             uint4* __restrict__ kp, uint4* __restrict__ vp)
{
    __shared__ unsigned short S_s[64 * kSStr];   // 17.4 KB bf16 [u][d]

    const int bid  = blockIdx.x;
    const int isV  = bid & 1;
    const int blk  = (bid >> 1) & 63;
    const int h    = bid >> 7;
    const int t    = threadIdx.x;
    const int lane = t & 63, n = lane & 15, quad = lane >> 4;
    const int wv   = t >> 6;                     // 0..3

    // phase 1: coalesced load 64x128 fp32 -> bf16 LDS
    {
        const float* src = (isV ? v : k) + ((size_t)blk * 64 * kH + h) * kD;
        const int r0 = t >> 5, c4 = (t & 31) << 2;
        #pragma unroll
        for (int p = 0; p < 8; ++p) {
            const int r = p * 8 + r0;
            const float4 f = *(const float4*)(src + (size_t)r * (kH * kD) + c4);
            *(unsigned int*)&S_s[r * kSStr + c4]     = pk_bf16(f.x, f.y);
            *(unsigned int*)&S_s[r * kSStr + c4 + 2] = pk_bf16(f.z, f.w);
        }
    }
    __syncthreads();

    const size_t obase = (size_t)(h * 64 + blk) * 16 * 64;
    if (!isV) {
        #pragma unroll
        for (int rep = 0; rep < 4; ++rep) {
            const int c = wv * 4 + rep;          // tt = wv, st = rep
            const int u = wv * 16 + n;
            kp[obase + (size_t)c * 64 + lane] =
                *(const uint4*)&S_s[u * kSStr + rep * 32 + quad * 8];
        }
    } else {
        #pragma unroll
        for (int rep = 0; rep < 4; ++rep) {
            const int c  = wv * 4 + rep;         // dt = c>>1, st = c&1
            const int d  = (c >> 1) * 16 + n;
            const int u0 = (c & 1) * 32 + quad * 8;
            unsigned short s[8];
            #pragma unroll
            for (int j = 0; j < 8; ++j) s[j] = S_s[(u0 + j) * kSStr + d];
            uint4 val;
            val.x = s[0] | ((unsigned)s[1] << 16);
            val.y = s[2] | ((unsigned)s[3] << 16);
            val.z = s[4] | ((unsigned)s[5] << 16);
            val.w = s[6] | ((unsigned)s[7] << 16);
            vp[obase + (size_t)c * 64 + lane] = val;
        }
    }
}

// ---------------- main kernel --------------------------------------------
__global__ __launch_bounds__(256, 2)
void hsa_main(const float* __restrict__ q, const float* __restrict__ w,
              const int* __restrict__ bidx, const uint4* __restrict__ kp,
              const uint4* __restrict__ vp, float* __restrict__ out)
{
    __shared__ __align__(16) unsigned short P_s[4 * kG * kPStr];
    __shared__ float O_red[kD * 17];             // [d][g], stride 17

    const int bid  = blockIdx.x;                 // 0..511
    const int l    = bid >> 1;
    const int h    = bid & 1;
    const int tid  = threadIdx.x;
    const int wave = tid >> 6;
    const int lane = tid & 63;
    const int n    = lane & 15;
    const int quad = lane >> 4;

    for (int i = tid; i < kD * 17; i += 256) O_red[i] = 0.f;

    // Q B-frags: lane g=n, k = st*32 + quad*8 + j
    s16x8 qf[4];
    {
        const float* qb = q + ((size_t)l * kHQ + h * kG + n) * kD + quad * 8;
        #pragma unroll
        for (int st = 0; st < 4; ++st) {
            const float4 f0 = *(const float4*)(qb + st * 32);
            const float4 f1 = *(const float4*)(qb + st * 32 + 4);
            union { s16x8 v; unsigned int u[4]; } z;
            z.u[0] = pk_bf16(f0.x, f0.y); z.u[1] = pk_bf16(f0.z, f0.w);
            z.u[2] = pk_bf16(f1.x, f1.y); z.u[3] = pk_bf16(f1.z, f1.w);
            qf[st] = z.v;
        }
    }

    // wave's 4 s-slots: block indices + per-lane weights (branchless invalid)
    const int4   bis = *(const int4*)(bidx + (size_t)(l * kH + h) * kS + wave * 4);
    const float4 wv4 = *(const float4*)(w + ((size_t)l * kHQ + h * kG + n) * kS + wave * 4);
    int   base_[4];
    float wval[4];
    {
        const int b[4] = {bis.x, bis.y, bis.z, bis.w};
        const float ww[4] = {wv4.x, wv4.y, wv4.z, wv4.w};
        #pragma unroll
        for (int j = 0; j < 4; ++j) {
            wval[j]  = (b[j] < 0) ? 0.f : ww[j];
            base_[j] = (h * kNB + max(b[j], 0)) * 16 * 64;   // uint4 idx
        }
    }

    __syncthreads();                             // O_red zeroed

    unsigned short* Pw = &P_s[wave * kG * kPStr];
    f32x4 oacc[8];
    #pragma unroll
    for (int dt = 0; dt < 8; ++dt) oacc[dt] = (f32x4){0.f, 0.f, 0.f, 0.f};

    // prologue: first block's K frags (16 loads in flight)
    FragU kreg[16];
    #pragma unroll
    for (int i = 0; i < 16; ++i) kreg[i].u = kp[base_[0] + i * 64 + lane];

    #pragma unroll
    for (int js = 0; js < 4; ++js) {
        // V frags for this block: issue before score MFMAs (independent)
        FragU vreg[16];
        #pragma unroll
        for (int i = 0; i < 16; ++i) vreg[i].u = vp[base_[js] + i * 64 + lane];

        // scores: S^T[u][g], 4 u-tiles
        f32x4 sc[4];
        #pragma unroll
        for (int t = 0; t < 4; ++t) sc[t] = (f32x4){0.f, 0.f, 0.f, 0.f};
        #pragma unroll
        for (int t = 0; t < 4; ++t)
            #pragma unroll
            for (int st = 0; st < 4; ++st)
                sc[t] = __builtin_amdgcn_mfma_f32_16x16x32_bf16(
                    kreg[t * 4 + st].v, qf[st], sc[t], 0, 0, 0);

        // prefetch next block's K (kreg dead after the MFMAs above)
        if (js < 3) {
            #pragma unroll
            for (int i = 0; i < 16; ++i) kreg[i].u = kp[base_[js + 1] + i * 64 + lane];
        }

        // intra-wave softmax over 64 u for g=n (exp in place)
        float part = 0.f;
        #pragma unroll
        for (int t = 0; t < 4; ++t)
            #pragma unroll
            for (int r = 0; r < 4; ++r) {
                sc[t][r] = exp2f(sc[t][r] * kScaleLog2e);
                part += sc[t][r];
            }
        part += __shfl_xor(part, 16);
        part += __shfl_xor(part, 32);
        const float coef = wval[js] / part;

        // P -> per-wave LDS slice (B-frag order); same-wave RAW, no barrier
        #pragma unroll
        for (int t = 0; t < 4; ++t) {
            const unsigned long long pq =
                ((unsigned long long)pk_bf16(sc[t][2] * coef, sc[t][3] * coef) << 32) |
                pk_bf16(sc[t][0] * coef, sc[t][1] * coef);
            *(unsigned long long*)&Pw[n * kPStr + t * 16 + quad * 4] = pq;
        }
        const s16x8 bf0 = *(const s16x8*)&Pw[n * kPStr + quad * 8];
        const s16x8 bf1 = *(const s16x8*)&Pw[n * kPStr + 32 + quad * 8];

        // PV: O^T[d][g] += V^T P^T, 8 d-tiles
        #pragma unroll
        for (int dt = 0; dt < 8; ++dt) {
            oacc[dt] = __builtin_amdgcn_mfma_f32_16x16x32_bf16(
                vreg[dt * 2 + 0].v, bf0, oacc[dt], 0, 0, 0);
            oacc[dt] = __builtin_amdgcn_mfma_f32_16x16x32_bf16(
                vreg[dt * 2 + 1].v, bf1, oacc[dt], 0, 0, 0);
        }
    }

    // combine 4 waves in LDS, then coalesced store
    #pragma unroll
    for (int dt = 0; dt < 8; ++dt)
        #pragma unroll
        for (int r = 0; r < 4; ++r)
            atomicAdd(&O_red[(dt * 16 + quad * 4 + r) * 17 + n], oacc[dt][r]);

    __syncthreads();

    {
        float* ob = out + ((size_t)l * kHQ + h * kG) * kD;
        #pragma unroll
        for (int rep = 0; rep < 2; ++rep) {
            const int idx = rep * 256 + tid;
            const int g = idx >> 5, d0 = (idx & 31) << 2;
            const float4 val = make_float4(O_red[(d0 + 0) * 17 + g],
                                           O_red[(d0 + 1) * 17 + g],
                                           O_red[(d0 + 2) * 17 + g],
                                           O_red[(d0 + 3) * 17 + g]);
            *(float4*)(ob + (size_t)g * kD + d0) = val;
        }
    }
}

} // namespace

extern "C" void kernel_launch(void* const* d_in, const int* in_sizes, int n_in,
                              void* d_out, int out_size, void* d_ws, size_t ws_size,
                              hipStream_t stream)
{
    const float* q    = (const float*)d_in[0];
    const float* k    = (const float*)d_in[1];
    const float* v    = (const float*)d_in[2];
    const float* w    = (const float*)d_in[3];
    const int*   bidx = (const int*)d_in[4];
    float* out = (float*)d_out;

    uint4* kp = (uint4*)d_ws;                                   // 2 MB
    uint4* vp = (uint4*)((char*)d_ws + (size_t)kKPackN * 16);   // 2 MB

    pack_kv<<<dim3(256), dim3(256), 0, stream>>>(k, v, kp, vp);
    hsa_main<<<dim3(kLq * kH), dim3(256), 0, stream>>>(q, w, bidx, kp, vp, out);
}

// Round 7
// 105.747 us; speedup vs baseline: 1.6115x; 1.0826x over previous
//
#include <hip/hip_runtime.h>
#include <hip/hip_bf16.h>

// HSA prefill R7 = R6 + forced memory-level parallelism.
// R6 post-mortem: VGPR_Count=60 proved the compiler sank every kp/vp load to
// its use (MLP~1 -> 128 serialized ~500cyc L2 loads/wave = 44.6us). Fix: pin
// issue order with __builtin_amdgcn_sched_barrier(0) so 16 loads stay in
// flight across each compute phase:
//   [vreg loads]|fence|[score MFMAs]|[kreg_next loads]|fence|[softmax+P]|[PV]
// waitcnt at first use then drains only the older 16 (vmcnt(16) pattern).

namespace {

constexpr int kLq = 256, kHQ = 32, kH = 2, kG = 16, kD = 128, kS = 16;
constexpr int kNB = 64;                    // Lkv/BS: distinct blocks per head
constexpr float kScaleLog2e = 0.08838834764831845f * 1.4426950408889634f;

constexpr int kKPackN = kH * kNB * 16 * 64;  // uint4 elems per array (2 MB)
constexpr int kPStr   = 72;                  // P slice g-stride (shorts)
constexpr int kSStr   = 136;                 // pack LDS row stride (shorts)

typedef short s16x8 __attribute__((ext_vector_type(8)));
typedef float f32x4 __attribute__((ext_vector_type(4)));

union U32BF2 { unsigned int u; __hip_bfloat162 h; };
union FragU  { uint4 u; s16x8 v; };

static __device__ inline unsigned int pk_bf16(float a, float b) {
    U32BF2 z; z.h = __float22bfloat162_rn(make_float2(a, b));
    return z.u;
}

// ---------------- pack kernel (unchanged from R6, ~9 us) -------------------
// grid 256: bid = h*128 + blk*2 + isV. 256 thr.
// K_packed idx = ((h*64+blk)*16 + t*4+st)*64 + lane (lane = quad*16+n)
//   holds K[u = blk*64 + t*16 + n][h][d = st*32 + quad*8 + j]
// V_packed idx = ((h*64+blk)*16 + dt*2+st)*64 + lane
//   holds V[u = blk*64 + st*32 + quad*8 + j][h][d = dt*16 + n]
__global__ __launch_bounds__(256)
void pack_kv(const float* __restrict__ k, const float* __restrict__ v,
             uint4* __restrict__ kp, uint4* __restrict__ vp)
{
    __shared__ unsigned short S_s[64 * kSStr];   // 17.4 KB bf16 [u][d]

    const int bid  = blockIdx.x;
    const int isV  = bid & 1;
    const int blk  = (bid >> 1) & 63;
    const int h    = bid >> 7;
    const int t    = threadIdx.x;
    const int lane = t & 63, n = lane & 15, quad = lane >> 4;
    const int wv   = t >> 6;                     // 0..3

    {
        const float* src = (isV ? v : k) + ((size_t)blk * 64 * kH + h) * kD;
        const int r0 = t >> 5, c4 = (t & 31) << 2;
        #pragma unroll
        for (int p = 0; p < 8; ++p) {
            const int r = p * 8 + r0;
            const float4 f = *(const float4*)(src + (size_t)r * (kH * kD) + c4);
            *(unsigned int*)&S_s[r * kSStr + c4]     = pk_bf16(f.x, f.y);
            *(unsigned int*)&S_s[r * kSStr + c4 + 2] = pk_bf16(f.z, f.w);
        }
    }
    __syncthreads();

    const size_t obase = (size_t)(h * 64 + blk) * 16 * 64;
    if (!isV) {
        #pragma unroll
        for (int rep = 0; rep < 4; ++rep) {
            const int u = wv * 16 + n;
            kp[obase + (size_t)(wv * 4 + rep) * 64 + lane] =
                *(const uint4*)&S_s[u * kSStr + rep * 32 + quad * 8];
        }
    } else {
        #pragma unroll
        for (int rep = 0; rep < 4; ++rep) {
            const int c  = wv * 4 + rep;         // dt = c>>1, st = c&1
            const int d  = (c >> 1) * 16 + n;
            const int u0 = (c & 1) * 32 + quad * 8;
            unsigned short s[8];
            #pragma unroll
            for (int j = 0; j < 8; ++j) s[j] = S_s[(u0 + j) * kSStr + d];
            uint4 val;
            val.x = s[0] | ((unsigned)s[1] << 16);
            val.y = s[2] | ((unsigned)s[3] << 16);
            val.z = s[4] | ((unsigned)s[5] << 16);
            val.w = s[6] | ((unsigned)s[7] << 16);
            vp[obase + (size_t)c * 64 + lane] = val;
        }
    }
}

// ---------------- main kernel --------------------------------------------
__global__ __launch_bounds__(256, 2)
void hsa_main(const float* __restrict__ q, const float* __restrict__ w,
              const int* __restrict__ bidx, const uint4* __restrict__ kp,
              const uint4* __restrict__ vp, float* __restrict__ out)
{
    __shared__ __align__(16) unsigned short P_s[4 * kG * kPStr];
    __shared__ float O_red[kD * 17];             // [d][g], stride 17

    const int bid  = blockIdx.x;                 // 0..511
    const int l    = bid >> 1;
    const int h    = bid & 1;
    const int tid  = threadIdx.x;
    const int wave = tid >> 6;
    const int lane = tid & 63;
    const int n    = lane & 15;
    const int quad = lane >> 4;

    for (int i = tid; i < kD * 17; i += 256) O_red[i] = 0.f;

    // Q B-frags: lane g=n, k = st*32 + quad*8 + j
    s16x8 qf[4];
    {
        const float* qb = q + ((size_t)l * kHQ + h * kG + n) * kD + quad * 8;
        #pragma unroll
        for (int st = 0; st < 4; ++st) {
            const float4 f0 = *(const float4*)(qb + st * 32);
            const float4 f1 = *(const float4*)(qb + st * 32 + 4);
            union { s16x8 v; unsigned int u[4]; } z;
            z.u[0] = pk_bf16(f0.x, f0.y); z.u[1] = pk_bf16(f0.z, f0.w);
            z.u[2] = pk_bf16(f1.x, f1.y); z.u[3] = pk_bf16(f1.z, f1.w);
            qf[st] = z.v;
        }
    }

    // wave's 4 s-slots: block indices + per-lane weights (branchless invalid)
    const int4   bis = *(const int4*)(bidx + (size_t)(l * kH + h) * kS + wave * 4);
    const float4 wv4 = *(const float4*)(w + ((size_t)l * kHQ + h * kG + n) * kS + wave * 4);
    int   base_[4];
    float wval[4];
    {
        const int b[4] = {bis.x, bis.y, bis.z, bis.w};
        const float ww[4] = {wv4.x, wv4.y, wv4.z, wv4.w};
        #pragma unroll
        for (int j = 0; j < 4; ++j) {
            wval[j]  = (b[j] < 0) ? 0.f : ww[j];
            base_[j] = (h * kNB + max(b[j], 0)) * 16 * 64;   // uint4 idx
        }
    }

    __syncthreads();                             // O_red zeroed

    unsigned short* Pw = &P_s[wave * kG * kPStr];
    f32x4 oacc[8];
    #pragma unroll
    for (int dt = 0; dt < 8; ++dt) oacc[dt] = (f32x4){0.f, 0.f, 0.f, 0.f};

    // prologue: first block's K frags (16 loads in flight)
    FragU kreg[16];
    #pragma unroll
    for (int i = 0; i < 16; ++i) kreg[i].u = kp[base_[0] + i * 64 + lane];
    __builtin_amdgcn_sched_barrier(0);

    #pragma unroll
    for (int js = 0; js < 4; ++js) {
        // V frags for this block: issue, then FENCE so they cannot sink.
        FragU vreg[16];
        #pragma unroll
        for (int i = 0; i < 16; ++i) vreg[i].u = vp[base_[js] + i * 64 + lane];
        __builtin_amdgcn_sched_barrier(0);

        // scores: S^T[u][g], 4 u-tiles (waits only on kreg; vreg in flight)
        f32x4 sc[4];
        #pragma unroll
        for (int t = 0; t < 4; ++t) sc[t] = (f32x4){0.f, 0.f, 0.f, 0.f};
        #pragma unroll
        for (int t = 0; t < 4; ++t)
            #pragma unroll
            for (int st = 0; st < 4; ++st)
                sc[t] = __builtin_amdgcn_mfma_f32_16x16x32_bf16(
                    kreg[t * 4 + st].v, qf[st], sc[t], 0, 0, 0);

        // prefetch next block's K (kreg dead), FENCE before softmax
        if (js < 3) {
            #pragma unroll
            for (int i = 0; i < 16; ++i) kreg[i].u = kp[base_[js + 1] + i * 64 + lane];
        }
        __builtin_amdgcn_sched_barrier(0);

        // intra-wave softmax over 64 u for g=n
        float part = 0.f;
        #pragma unroll
        for (int t = 0; t < 4; ++t)
            #pragma unroll
            for (int r = 0; r < 4; ++r) {
                sc[t][r] = exp2f(sc[t][r] * kScaleLog2e);
                part += sc[t][r];
            }
        part += __shfl_xor(part, 16);
        part += __shfl_xor(part, 32);
        const float coef = wval[js] / part;

        // P -> per-wave LDS slice (B-frag order); same-wave RAW, no barrier
        #pragma unroll
        for (int t = 0; t < 4; ++t) {
            const unsigned long long pq =
                ((unsigned long long)pk_bf16(sc[t][2] * coef, sc[t][3] * coef) << 32) |
                pk_bf16(sc[t][0] * coef, sc[t][1] * coef);
            *(unsigned long long*)&Pw[n * kPStr + t * 16 + quad * 4] = pq;
        }
        const s16x8 bf0 = *(const s16x8*)&Pw[n * kPStr + quad * 8];
        const s16x8 bf1 = *(const s16x8*)&Pw[n * kPStr + 32 + quad * 8];

        // PV: O^T[d][g] += V^T P^T (waits drain vreg; kreg_next in flight)
        #pragma unroll
        for (int dt = 0; dt < 8; ++dt) {
            oacc[dt] = __builtin_amdgcn_mfma_f32_16x16x32_bf16(
                vreg[dt * 2 + 0].v, bf0, oacc[dt], 0, 0, 0);
            oacc[dt] = __builtin_amdgcn_mfma_f32_16x16x32_bf16(
                vreg[dt * 2 + 1].v, bf1, oacc[dt], 0, 0, 0);
        }
        __builtin_amdgcn_sched_barrier(0);
    }

    // combine 4 waves in LDS, then coalesced store
    #pragma unroll
    for (int dt = 0; dt < 8; ++dt)
        #pragma unroll
        for (int r = 0; r < 4; ++r)
            atomicAdd(&O_red[(dt * 16 + quad * 4 + r) * 17 + n], oacc[dt][r]);

    __syncthreads();

    {
        float* ob = out + ((size_t)l * kHQ + h * kG) * kD;
        #pragma unroll
        for (int rep = 0; rep < 2; ++rep) {
            const int idx = rep * 256 + tid;
            const int g = idx >> 5, d0 = (idx & 31) << 2;
            const float4 val = make_float4(O_red[(d0 + 0) * 17 + g],
                                           O_red[(d0 + 1) * 17 + g],
                                           O_red[(d0 + 2) * 17 + g],
                                           O_red[(d0 + 3) * 17 + g]);
            *(float4*)(ob + (size_t)g * kD + d0) = val;
        }
    }
}

} // namespace

extern "C" void kernel_launch(void* const* d_in, const int* in_sizes, int n_in,
                              void* d_out, int out_size, void* d_ws, size_t ws_size,
                              hipStream_t stream)
{
    const float* q    = (const float*)d_in[0];
    const float* k    = (const float*)d_in[1];
    const float* v    = (const float*)d_in[2];
    const float* w    = (const float*)d_in[3];
    const int*   bidx = (const int*)d_in[4];
    float* out = (float*)d_out;

    uint4* kp = (uint4*)d_ws;                                   // 2 MB
    uint4* vp = (uint4*)((char*)d_ws + (size_t)kKPackN * 16);   // 2 MB

    pack_kv<<<dim3(256), dim3(256), 0, stream>>>(k, v, kp, vp);
    hsa_main<<<dim3(kLq * kH), dim3(256), 0, stream>>>(q, w, bidx, kp, vp, out);
}

// Round 9
// 102.071 us; speedup vs baseline: 1.6695x; 1.0360x over previous
//
#include <hip/hip_runtime.h>
#include <hip/hip_bf16.h>

// HSA prefill R9: async LDS double-buffer with SAFE barriers.
// R8 post-mortem: raw s_barrier + inline-asm vmcnt(8) raced under graph
// replay (first validation passed, replay validation failed). R9 keeps the
// same structure but uses __syncthreads() only, with the prefetch issued a
// FULL compute-phase before the barrier -> its vmcnt(0) drain is ~free
// because the 8 staging loads (~500-900 cyc latency) complete during the
// ~1500 cyc compute phase. One barrier per block iteration.
//
// wg=(l,h), 4 waves; per block: all waves cooperatively stage K,V frags of
// block js+1 via global_load_lds (zero VGPR cost), compute block js from
// LDS: each wave computes the FULL 64ux16g score tile redundantly (buys
// fully intra-wave softmax, no cross-wave reductions), owns 2 PV d-tiles,
// direct coalesced O stores (no atomics, no LDS O-reduction).

namespace {

constexpr int kLq = 256, kHQ = 32, kH = 2, kG = 16, kD = 128, kS = 16;
constexpr int kNB = 64;                    // Lkv/BS: distinct blocks per head
constexpr float kScaleLog2e = 0.08838834764831845f * 1.4426950408889634f;

constexpr int kKPackN = kH * kNB * 16 * 64;  // uint4 elems per array (2 MB)
constexpr int kPStr   = 72;                  // P slice g-stride (shorts)
constexpr int kSStr   = 136;                 // pack LDS row stride (shorts)

typedef short s16x8 __attribute__((ext_vector_type(8)));
typedef float f32x4 __attribute__((ext_vector_type(4)));

union U32BF2 { unsigned int u; __hip_bfloat162 h; };

static __device__ inline unsigned int pk_bf16(float a, float b) {
    U32BF2 z; z.h = __float22bfloat162_rn(make_float2(a, b));
    return z.u;
}

// ---------------- pack kernel (unchanged from R6, ~9 us) -------------------
// K_packed idx = ((h*64+blk)*16 + t*4+st)*64 + lane (lane = quad*16+n)
//   holds K[u = blk*64 + t*16 + n][h][d = st*32 + quad*8 + j]
// V_packed idx = ((h*64+blk)*16 + dt*2+st)*64 + lane
//   holds V[u = blk*64 + st*32 + quad*8 + j][h][d = dt*16 + n]
__global__ __launch_bounds__(256)
void pack_kv(const float* __restrict__ k, const float* __restrict__ v,
             uint4* __restrict__ kp, uint4* __restrict__ vp)
{
    __shared__ unsigned short S_s[64 * kSStr];   // 17.4 KB bf16 [u][d]

    const int bid  = blockIdx.x;
    const int isV  = bid & 1;
    const int blk  = (bid >> 1) & 63;
    const int h    = bid >> 7;
    const int t    = threadIdx.x;
    const int lane = t & 63, n = lane & 15, quad = lane >> 4;
    const int wv   = t >> 6;                     // 0..3

    {
        const float* src = (isV ? v : k) + ((size_t)blk * 64 * kH + h) * kD;
        const int r0 = t >> 5, c4 = (t & 31) << 2;
        #pragma unroll
        for (int p = 0; p < 8; ++p) {
            const int r = p * 8 + r0;
            const float4 f = *(const float4*)(src + (size_t)r * (kH * kD) + c4);
            *(unsigned int*)&S_s[r * kSStr + c4]     = pk_bf16(f.x, f.y);
            *(unsigned int*)&S_s[r * kSStr + c4 + 2] = pk_bf16(f.z, f.w);
        }
    }
    __syncthreads();

    const size_t obase = (size_t)(h * 64 + blk) * 16 * 64;
    if (!isV) {
        #pragma unroll
        for (int rep = 0; rep < 4; ++rep) {
            const int u = wv * 16 + n;
            kp[obase + (size_t)(wv * 4 + rep) * 64 + lane] =
                *(const uint4*)&S_s[u * kSStr + rep * 32 + quad * 8];
        }
    } else {
        #pragma unroll
        for (int rep = 0; rep < 4; ++rep) {
            const int c  = wv * 4 + rep;         // dt = c>>1, st = c&1
            const int d  = (c >> 1) * 16 + n;
            const int u0 = (c & 1) * 32 + quad * 8;
            unsigned short s[8];
            #pragma unroll
            for (int j = 0; j < 8; ++j) s[j] = S_s[(u0 + j) * kSStr + d];
            uint4 val;
            val.x = s[0] | ((unsigned)s[1] << 16);
            val.y = s[2] | ((unsigned)s[3] << 16);
            val.z = s[4] | ((unsigned)s[5] << 16);
            val.w = s[6] | ((unsigned)s[7] << 16);
            vp[obase + (size_t)c * 64 + lane] = val;
        }
    }
}

// ---------------- main kernel --------------------------------------------
__global__ __launch_bounds__(256, 2)
void hsa_main(const float* __restrict__ q, const float* __restrict__ w,
              const int* __restrict__ bidx, const uint4* __restrict__ kp,
              const uint4* __restrict__ vp, float* __restrict__ out)
{
    // frag f (0..15 = K, 16..31 = V) lives at buf[b][f*64 + lane]
    __shared__ __align__(16) uint4 buf[2][32 * 64];               // 64 KB
    __shared__ __align__(16) unsigned short P_s[4 * kG * kPStr];  // 9.2 KB

    const int bid  = blockIdx.x;                 // 0..511
    const int l    = bid >> 1;
    const int h    = bid & 1;
    const int tid  = threadIdx.x;
    const int wave = tid >> 6;
    const int lane = tid & 63;
    const int n    = lane & 15;
    const int quad = lane >> 4;

    // Q B-frags: lane g=n, k = st*32 + quad*8 + j
    s16x8 qf[4];
    {
        const float* qb = q + ((size_t)l * kHQ + h * kG + n) * kD + quad * 8;
        #pragma unroll
        for (int st = 0; st < 4; ++st) {
            const float4 f0 = *(const float4*)(qb + st * 32);
            const float4 f1 = *(const float4*)(qb + st * 32 + 4);
            union { s16x8 v; unsigned int u[4]; } z;
            z.u[0] = pk_bf16(f0.x, f0.y); z.u[1] = pk_bf16(f0.z, f0.w);
            z.u[2] = pk_bf16(f1.x, f1.y); z.u[3] = pk_bf16(f1.z, f1.w);
            qf[st] = z.v;
        }
    }

    // all 16 s-slots: block bases (uniform) + per-lane weights (branchless)
    int   base_[kS];
    float wval[kS];
    #pragma unroll
    for (int i = 0; i < 4; ++i) {
        const int4   b4 = *(const int4*)(bidx + (size_t)(l * kH + h) * kS + i * 4);
        const float4 w4 = *(const float4*)(w + ((size_t)l * kHQ + h * kG + n) * kS + i * 4);
        const int   bb[4] = {b4.x, b4.y, b4.z, b4.w};
        const float ww[4] = {w4.x, w4.y, w4.z, w4.w};
        #pragma unroll
        for (int jj = 0; jj < 4; ++jj) {
            wval[i * 4 + jj]  = (bb[jj] < 0) ? 0.f : ww[jj];
            base_[i * 4 + jj] = (h * kNB + max(bb[jj], 0)) * 1024;  // uint4 idx
        }
    }

    // wave stages frags [wave*8, wave*8+8): waves 0,1 -> K, waves 2,3 -> V
    const int    f0    = wave * 8;
    const uint4* gsrc  = (f0 < 16) ? kp : vp;
    const int    fbase = (f0 < 16) ? f0 * 64 : (f0 - 16) * 64;

    #define STAGE(js_, b_)                                                     \
        {                                                                      \
            const uint4* gp = gsrc + base_[(js_)] + fbase + lane;              \
            auto* lp = (__attribute__((address_space(3))) uint4*)&buf[(b_)][f0 * 64]; \
            _Pragma("unroll")                                                  \
            for (int i_ = 0; i_ < 8; ++i_)                                     \
                __builtin_amdgcn_global_load_lds(                              \
                    (const __attribute__((address_space(1))) void*)(gp + i_ * 64), \
                    (__attribute__((address_space(3))) void*)(lp + i_ * 64),   \
                    16, 0, 0);                                                 \
        }

    STAGE(0, 0);
    __syncthreads();                       // startup: buf[0] fully staged

    unsigned short* Pw = &P_s[wave * kG * kPStr];
    f32x4 oacc0 = {0.f, 0.f, 0.f, 0.f};   // d-tile 2*wave
    f32x4 oacc1 = {0.f, 0.f, 0.f, 0.f};   // d-tile 2*wave+1

    #pragma unroll
    for (int js = 0; js < kS; ++js) {
        const int cur = js & 1;

        // prefetch next block a FULL compute-phase ahead of the barrier
        if (js < kS - 1) {
            STAGE(js + 1, cur ^ 1);
            __builtin_amdgcn_sched_barrier(0);   // pin issue point
        }

        // ---- scores: full 64u x 16g tile per wave (redundant, barrier-free) ----
        f32x4 sc[4];
        #pragma unroll
        for (int t = 0; t < 4; ++t) sc[t] = (f32x4){0.f, 0.f, 0.f, 0.f};
        #pragma unroll
        for (int t = 0; t < 4; ++t)
            #pragma unroll
            for (int st = 0; st < 4; ++st) {
                const s16x8 af = *(const s16x8*)&buf[cur][(t * 4 + st) * 64 + lane];
                sc[t] = __builtin_amdgcn_mfma_f32_16x16x32_bf16(af, qf[st], sc[t], 0, 0, 0);
            }

        // ---- fully intra-wave softmax over 64 u for g=n ----
        float part = 0.f;
        #pragma unroll
        for (int t = 0; t < 4; ++t)
            #pragma unroll
            for (int r = 0; r < 4; ++r) {
                sc[t][r] = exp2f(sc[t][r] * kScaleLog2e);
                part += sc[t][r];
            }
        part += __shfl_xor(part, 16);
        part += __shfl_xor(part, 32);
        const float coef = wval[js] / part;

        // ---- P -> own LDS slice (B-frag order); same-wave RAW ----
        #pragma unroll
        for (int t = 0; t < 4; ++t) {
            const unsigned long long pq =
                ((unsigned long long)pk_bf16(sc[t][2] * coef, sc[t][3] * coef) << 32) |
                pk_bf16(sc[t][0] * coef, sc[t][1] * coef);
            *(unsigned long long*)&Pw[n * kPStr + t * 16 + quad * 4] = pq;
        }
        const s16x8 bf0 = *(const s16x8*)&Pw[n * kPStr + quad * 8];
        const s16x8 bf1 = *(const s16x8*)&Pw[n * kPStr + 32 + quad * 8];

        // ---- PV: wave owns d-tiles {2w, 2w+1} (V frags 16 + dt*2 + st) ----
        {
            const int dt0 = wave * 2;
            const s16x8 a00 = *(const s16x8*)&buf[cur][(16 + dt0 * 2 + 0) * 64 + lane];
            const s16x8 a01 = *(const s16x8*)&buf[cur][(16 + dt0 * 2 + 1) * 64 + lane];
            oacc0 = __builtin_amdgcn_mfma_f32_16x16x32_bf16(a00, bf0, oacc0, 0, 0, 0);
            oacc0 = __builtin_amdgcn_mfma_f32_16x16x32_bf16(a01, bf1, oacc0, 0, 0, 0);
            const s16x8 a10 = *(const s16x8*)&buf[cur][(16 + dt0 * 2 + 2) * 64 + lane];
            const s16x8 a11 = *(const s16x8*)&buf[cur][(16 + dt0 * 2 + 3) * 64 + lane];
            oacc1 = __builtin_amdgcn_mfma_f32_16x16x32_bf16(a10, bf0, oacc1, 0, 0, 0);
            oacc1 = __builtin_amdgcn_mfma_f32_16x16x32_bf16(a11, bf1, oacc1, 0, 0, 0);
        }

        // one barrier per iteration: joins (a) all reads of buf[cur] done,
        // (b) all waves' prefetch DMA for buf[nxt] drained (vmcnt(0) is ~free
        // here -- the loads had the whole compute phase to complete).
        __syncthreads();
    }
    #undef STAGE

    // ---- epilogue: each output element owned by exactly one wave ----
    {
        float* ob = out + ((size_t)l * kHQ + h * kG + n) * kD;
        const int d0 = wave * 32 + quad * 4;
        *(float4*)(ob + d0)      = make_float4(oacc0[0], oacc0[1], oacc0[2], oacc0[3]);
        *(float4*)(ob + d0 + 16) = make_float4(oacc1[0], oacc1[1], oacc1[2], oacc1[3]);
    }
}

} // namespace

extern "C" void kernel_launch(void* const* d_in, const int* in_sizes, int n_in,
                              void* d_out, int out_size, void* d_ws, size_t ws_size,
                              hipStream_t stream)
{
    const float* q    = (const float*)d_in[0];
    const float* k    = (const float*)d_in[1];
    const float* v    = (const float*)d_in[2];
    const float* w    = (const float*)d_in[3];
    const int*   bidx = (const int*)d_in[4];
    float* out = (float*)d_out;

    uint4* kp = (uint4*)d_ws;                                   // 2 MB
    uint4* vp = (uint4*)((char*)d_ws + (size_t)kKPackN * 16);   // 2 MB

    pack_kv<<<dim3(256), dim3(256), 0, stream>>>(k, v, kp, vp);
    hsa_main<<<dim3(kLq * kH), dim3(256), 0, stream>>>(q, w, bidx, kp, vp, out);
}

// Round 10
// 97.116 us; speedup vs baseline: 1.7547x; 1.0510x over previous
//
#include <hip/hip_runtime.h>
#include <hip/hip_bf16.h>

// HSA prefill R10: non-redundant scores + single barrier per block.
// R9 model: 4x-redundant score tile made the LDS pipe the bottleneck
// (~26 LDS ops/wave/iter) and quadrupled exp2. Now: wave w computes only
// u-tile w (4 MFMAs, K frags from GLOBAL into 4 prefetched regs), softmax
// denominator is assembled cross-wave with ONE barrier via deferred
// normalization: P stored UNNORMALIZED (bf16), psum partials in LDS; after
// the barrier each wave reads 4 psums, coef = w/sum is per-lane (lane n owns
// output column g=n), PV goes into a fresh pacc and oacc += coef*pacc.
// V staged via global_load_lds double-buffer (prefetch dist 1, drained by the
// NEXT iter's __syncthreads -- a full compute phase later). LDS 37 KB ->
// 3 wg/CU (launch_bounds(256,3), VGPR cap 170: no R4-style spills).
// pack_kv split into 512 wgs (half-blocks) to halve its latency.

namespace {

constexpr int kLq = 256, kHQ = 32, kH = 2, kG = 16, kD = 128, kS = 16;
constexpr int kNB = 64;                    // Lkv/BS: distinct blocks per head
constexpr float kScaleLog2e = 0.08838834764831845f * 1.4426950408889634f;

constexpr int kKPackN = kH * kNB * 16 * 64;  // uint4 elems per array (2 MB)
constexpr int kPStr   = 72;                  // P row stride (shorts), 16B-mult
constexpr int kSStr   = 136;                 // pack LDS row stride (shorts)

typedef short s16x8 __attribute__((ext_vector_type(8)));
typedef float f32x4 __attribute__((ext_vector_type(4)));

union U32BF2 { unsigned int u; __hip_bfloat162 h; };
union FragU  { uint4 u; s16x8 v; };

static __device__ inline unsigned int pk_bf16(float a, float b) {
    U32BF2 z; z.h = __float22bfloat162_rn(make_float2(a, b));
    return z.u;
}

// ---------------- pack kernel: 512 wgs, each handles half a block ----------
// K_packed idx = ((h*64+blk)*16 + t*4+st)*64 + lane (lane = quad*16+n)
//   holds K[u = blk*64 + t*16 + n][h][d = st*32 + quad*8 + j]
// V_packed idx = ((h*64+blk)*16 + dt*2+st)*64 + lane
//   holds V[u = blk*64 + st*32 + quad*8 + j][h][d = dt*16 + n]
// half owns u rows [half*32, half*32+32): K frags t in {2half,2half+1},
// V frags with st == half.
__global__ __launch_bounds__(256)
void pack_kv(const float* __restrict__ k, const float* __restrict__ v,
             uint4* __restrict__ kp, uint4* __restrict__ vp)
{
    __shared__ unsigned short S_s[32 * kSStr];   // 8.7 KB bf16 [u_loc][d]

    const int bid  = blockIdx.x;                 // 0..511
    const int isV  = bid & 1;
    const int half = (bid >> 1) & 1;
    const int blk  = (bid >> 2) & 63;
    const int h    = bid >> 8;
    const int t    = threadIdx.x;
    const int lane = t & 63, n = lane & 15, quad = lane >> 4;
    const int wv   = t >> 6;                     // 0..3

    {   // coalesced load 32 rows x 128 fp32 -> bf16 LDS
        const float* src = (isV ? v : k) +
            ((size_t)(blk * 64 + half * 32) * kH + h) * kD;
        const int r0 = t >> 5, c4 = (t & 31) << 2;
        #pragma unroll
        for (int p = 0; p < 4; ++p) {
            const int r = p * 8 + r0;
            const float4 f = *(const float4*)(src + (size_t)r * (kH * kD) + c4);
            *(unsigned int*)&S_s[r * kSStr + c4]     = pk_bf16(f.x, f.y);
            *(unsigned int*)&S_s[r * kSStr + c4 + 2] = pk_bf16(f.z, f.w);
        }
    }
    __syncthreads();

    const size_t obase = (size_t)(h * 64 + blk) * 16 * 64;
    if (!isV) {
        #pragma unroll
        for (int rep = 0; rep < 2; ++rep) {
            const int cl    = wv * 2 + rep;      // 0..7
            const int t_loc = cl >> 2, st = cl & 3;
            const int c     = (2 * half + t_loc) * 4 + st;
            const int u_loc = t_loc * 16 + n;
            kp[obase + (size_t)c * 64 + lane] =
                *(const uint4*)&S_s[u_loc * kSStr + st * 32 + quad * 8];
        }
    } else {
        #pragma unroll
        for (int rep = 0; rep < 2; ++rep) {
            const int dt = wv * 2 + rep;         // 0..7
            const int c  = dt * 2 + half;
            const int d  = dt * 16 + n;
            unsigned short s[8];
            #pragma unroll
            for (int j = 0; j < 8; ++j) s[j] = S_s[(quad * 8 + j) * kSStr + d];
            uint4 val;
            val.x = s[0] | ((unsigned)s[1] << 16);
            val.y = s[2] | ((unsigned)s[3] << 16);
            val.z = s[4] | ((unsigned)s[5] << 16);
            val.w = s[6] | ((unsigned)s[7] << 16);
            vp[obase + (size_t)c * 64 + lane] = val;
        }
    }
}

// ---------------- main kernel --------------------------------------------
__global__ __launch_bounds__(256, 3)
void hsa_main(const float* __restrict__ q, const float* __restrict__ w,
              const int* __restrict__ bidx, const uint4* __restrict__ kp,
              const uint4* __restrict__ vp, float* __restrict__ out)
{
    __shared__ __align__(16) uint4 vbuf[2][16 * 64];               // 32 KB
    __shared__ __align__(16) unsigned short P_s[2][kG * kPStr];    // 4.6 KB
    __shared__ __align__(16) float psum[2][kG][4];                 // 512 B

    const int bid  = blockIdx.x;                 // 0..511
    const int l    = bid >> 1;
    const int h    = bid & 1;
    const int tid  = threadIdx.x;
    const int wave = tid >> 6;
    const int lane = tid & 63;
    const int n    = lane & 15;
    const int quad = lane >> 4;

    // Q B-frags: lane g=n, k = st*32 + quad*8 + j
    s16x8 qf[4];
    {
        const float* qb = q + ((size_t)l * kHQ + h * kG + n) * kD + quad * 8;
        #pragma unroll
        for (int st = 0; st < 4; ++st) {
            const float4 f0 = *(const float4*)(qb + st * 32);
            const float4 f1 = *(const float4*)(qb + st * 32 + 4);
            union { s16x8 v; unsigned int u[4]; } z;
            z.u[0] = pk_bf16(f0.x, f0.y); z.u[1] = pk_bf16(f0.z, f0.w);
            z.u[2] = pk_bf16(f1.x, f1.y); z.u[3] = pk_bf16(f1.z, f1.w);
            qf[st] = z.v;
        }
    }

    // all 16 s-slots: block bases (uniform) + per-lane weights (branchless)
    int   base_[kS];
    float wval[kS];
    #pragma unroll
    for (int i = 0; i < 4; ++i) {
        const int4   b4 = *(const int4*)(bidx + (size_t)(l * kH + h) * kS + i * 4);
        const float4 w4 = *(const float4*)(w + ((size_t)l * kHQ + h * kG + n) * kS + i * 4);
        const int   bb[4] = {b4.x, b4.y, b4.z, b4.w};
        const float ww[4] = {w4.x, w4.y, w4.z, w4.w};
        #pragma unroll
        for (int jj = 0; jj < 4; ++jj) {
            wval[i * 4 + jj]  = (bb[jj] < 0) ? 0.f : ww[jj];
            base_[i * 4 + jj] = (h * kNB + max(bb[jj], 0)) * 1024;  // uint4 idx
        }
    }

    // each wave stages V frags [wave*4, wave*4+4) of the given block
    #define STAGE_V(js_, b_)                                                   \
        {                                                                      \
            const uint4* gp = vp + base_[(js_)] + (wave * 4) * 64 + lane;      \
            auto* lp = (__attribute__((address_space(3))) uint4*)              \
                           &vbuf[(b_)][(wave * 4) * 64];                       \
            _Pragma("unroll")                                                  \
            for (int i_ = 0; i_ < 4; ++i_)                                     \
                __builtin_amdgcn_global_load_lds(                              \
                    (const __attribute__((address_space(1))) void*)(gp + i_ * 64), \
                    (__attribute__((address_space(3))) void*)(lp + i_ * 64),   \
                    16, 0, 0);                                                 \
        }

    // prologue: V[0] staging + K[0] frags in flight (drained at C(0))
    STAGE_V(0, 0);
    FragU kreg[4];
    #pragma unroll
    for (int st = 0; st < 4; ++st)
        kreg[st].u = kp[base_[0] + (wave * 4 + st) * 64 + lane];
    __builtin_amdgcn_sched_barrier(0);

    f32x4 oacc0 = {0.f, 0.f, 0.f, 0.f};   // d-tile 2*wave
    f32x4 oacc1 = {0.f, 0.f, 0.f, 0.f};   // d-tile 2*wave+1

    #pragma unroll
    for (int js = 0; js < kS; ++js) {
        const int cur = js & 1;

        // ---- scores: wave owns u-tile = wave (u = wave*16 + quad*4 + r) ----
        f32x4 sc = {0.f, 0.f, 0.f, 0.f};
        #pragma unroll
        for (int st = 0; st < 4; ++st)
            sc = __builtin_amdgcn_mfma_f32_16x16x32_bf16(kreg[st].v, qf[st], sc, 0, 0, 0);

        // prefetch next block's K frags (kreg dead after MFMAs above)
        if (js < kS - 1) {
            #pragma unroll
            for (int st = 0; st < 4; ++st)
                kreg[st].u = kp[base_[js + 1] + (wave * 4 + st) * 64 + lane];
        }
        __builtin_amdgcn_sched_barrier(0);

        // ---- exp (4 values/lane) + wave-partial denominator ----
        float part = 0.f;
        #pragma unroll
        for (int r = 0; r < 4; ++r) {
            sc[r] = exp2f(sc[r] * kScaleLog2e);
            part += sc[r];
        }
        part += __shfl_xor(part, 16);
        part += __shfl_xor(part, 32);      // all quads of column n share partial
        if (quad == 0) psum[cur][n][wave] = part;

        // ---- UNNORMALIZED P -> shared LDS (B-frag order) ----
        const unsigned long long pq =
            ((unsigned long long)pk_bf16(sc[2], sc[3]) << 32) | pk_bf16(sc[0], sc[1]);
        *(unsigned long long*)&P_s[cur][n * kPStr + wave * 16 + quad * 4] = pq;

        __syncthreads();                   // C(js): psum+P visible; V[js] DMA drained

        // ---- denominator + per-lane coef (lane n owns output column g=n) ----
        const float4 ps  = *(const float4*)&psum[cur][n][0];
        const float coef = wval[js] / (ps.x + ps.y + ps.z + ps.w);
        const s16x8 bf0 = *(const s16x8*)&P_s[cur][n * kPStr + quad * 8];
        const s16x8 bf1 = *(const s16x8*)&P_s[cur][n * kPStr + 32 + quad * 8];

        // ---- issue V[js+1] staging (drained by C(js+1), a full phase away) ----
        if (js < kS - 1) { STAGE_V(js + 1, cur ^ 1); }
        __builtin_amdgcn_sched_barrier(0);

        // ---- PV into fresh pacc, then oacc += coef * pacc ----
        const f32x4 zero = {0.f, 0.f, 0.f, 0.f};
        const s16x8 a0 = *(const s16x8*)&vbuf[cur][(wave * 4 + 0) * 64 + lane];
        const s16x8 a1 = *(const s16x8*)&vbuf[cur][(wave * 4 + 1) * 64 + lane];
        const s16x8 a2 = *(const s16x8*)&vbuf[cur][(wave * 4 + 2) * 64 + lane];
        const s16x8 a3 = *(const s16x8*)&vbuf[cur][(wave * 4 + 3) * 64 + lane];
        f32x4 p0 = __builtin_amdgcn_mfma_f32_16x16x32_bf16(a0, bf0, zero, 0, 0, 0);
        p0       = __builtin_amdgcn_mfma_f32_16x16x32_bf16(a1, bf1, p0,   0, 0, 0);
        f32x4 p1 = __builtin_amdgcn_mfma_f32_16x16x32_bf16(a2, bf0, zero, 0, 0, 0);
        p1       = __builtin_amdgcn_mfma_f32_16x16x32_bf16(a3, bf1, p1,   0, 0, 0);
        #pragma unroll
        for (int r = 0; r < 4; ++r) {
            oacc0[r] = fmaf(coef, p0[r], oacc0[r]);
            oacc1[r] = fmaf(coef, p1[r], oacc1[r]);
        }
    }
    #undef STAGE_V

    // ---- epilogue: each output element owned by exactly one wave ----
    {
        float* ob = out + ((size_t)l * kHQ + h * kG + n) * kD;
        const int d0 = wave * 32 + quad * 4;
        *(float4*)(ob + d0)      = make_float4(oacc0[0], oacc0[1], oacc0[2], oacc0[3]);
        *(float4*)(ob + d0 + 16) = make_float4(oacc1[0], oacc1[1], oacc1[2], oacc1[3]);
    }
}

} // namespace

extern "C" void kernel_launch(void* const* d_in, const int* in_sizes, int n_in,
                              void* d_out, int out_size, void* d_ws, size_t ws_size,
                              hipStream_t stream)
{
    const float* q    = (const float*)d_in[0];
    const float* k    = (const float*)d_in[1];
    const float* v    = (const float*)d_in[2];
    const float* w    = (const float*)d_in[3];
    const int*   bidx = (const int*)d_in[4];
    float* out = (float*)d_out;

    uint4* kp = (uint4*)d_ws;                                   // 2 MB
    uint4* vp = (uint4*)((char*)d_ws + (size_t)kKPackN * 16);   // 2 MB

    pack_kv<<<dim3(512), dim3(256), 0, stream>>>(k, v, kp, vp);
    hsa_main<<<dim3(kLq * kH), dim3(256), 0, stream>>>(q, w, bidx, kp, vp, out);
}